// Round 6
// baseline (762.829 us; speedup 1.0000x reference)
//
#include <hip/hip_runtime.h>
#include <hip/hip_fp16.h>

#define C_   256
#define H_   224
#define W_   224
#define HW_  (224 * 224)
#define NWH  28
#define NWW  28
#define NWIN 3136
#define NQUAD 784             // 4 b * 28 wh * 7 quads (4 windows each)
#define NTILE 64              // 48 qkv tiles + 16 out-proj tiles
#define NFRAG (NTILE * 8 * 64)

#define XN_OFF  1048576ULL                                  // ws byte offsets
#define O_OFF   (XN_OFF + (unsigned long long)NWIN * 32768ULL)
#define WS_NEED (O_OFF + (unsigned long long)NWIN * 32768ULL)  // ~207 MB (confirmed fits: R5 ran this path)

typedef _Float16 f16x8 __attribute__((ext_vector_type(8)));
typedef float    f32x4 __attribute__((ext_vector_type(4)));

// ---- weight fp32 -> fragment-major fp16 (B-frag for mfma_f32_16x16x32_f16) --
__global__ void wcvt_kernel(const float* __restrict__ wqkv,
                            const float* __restrict__ wout,
                            _Float16* __restrict__ dst) {
  int f = blockIdx.x * blockDim.x + threadIdx.x;
  if (f >= NFRAG) return;
  int lane = f & 63, kk = (f >> 6) & 7, tile = f >> 9;
  int row = tile * 16 + (lane & 15);
  int col = kk * 32 + (lane >> 4) * 8;
  const float* src = (tile < 48) ? (wqkv + row * 256 + col)
                                 : (wout + (row - 768) * 256 + col);
  f32x4 a = *(const f32x4*)src;
  f32x4 b2 = *(const f32x4*)(src + 4);
  f16x8 r;
#pragma unroll
  for (int q = 0; q < 4; ++q) { r[q] = (_Float16)a[q]; r[q + 4] = (_Float16)b2[q]; }
  *(f16x8*)(dst + (size_t)f * 8) = r;
}

// ---- swizzled LDS accessors (bijective XOR in byte[6:4]; 16B-aligned) -------
__device__ __forceinline__ _Float16* xn_at(char* s, int row, int col) {
  return (_Float16*)(s + ((row * 512 + col * 2) ^ ((row & 7) << 4)));
}
__device__ __forceinline__ _Float16* qk_at(char* b, int row, int col) {
  return (_Float16*)(b + ((row * 64 + col * 2) ^ (((row >> 1) & 3) << 4)));
}
__device__ __forceinline__ _Float16* p_at(char* b, int row, int col) {
  return (_Float16*)(b + ((row * 128 + col * 2) ^ ((row & 7) << 4)));
}
__device__ __forceinline__ _Float16* vt_at(char* b, int d, int k) {
  return (_Float16*)(b + ((d * 128 + k * 2) ^ ((d & 7) << 4)));
}

__device__ __forceinline__ f16x8 frag16(const _Float16* __restrict__ w16,
                                        int gt, int kk, int lane) {
  return *(const f16x8*)(w16 + ((size_t)((gt * 8 + kk) * 64 + lane)) * 8);
}

// ============================ kernel A: prep =================================
__global__ __launch_bounds__(512, 1) void prep_kernel(
    const float* __restrict__ x, const float* __restrict__ gamma,
    const float* __restrict__ beta, _Float16* __restrict__ xn_ws) {
  extern __shared__ char smem[];
  float* red = (float*)(smem + 131072);
  float* mrs = (float*)(smem + 147456);
  const int n0 = blockIdx.x;
  const int b  = n0 / 196;
  const int rem = n0 % 196;
  const int wh = rem / 7;
  const int wq = rem % 7;
  const int tid = threadIdx.x;
  const int px4 = (tid & 7) * 4;
  const int row = (tid >> 3) & 7;
  const int chg = tid >> 6;
  const int win = px4 >> 3;
  const int pc  = px4 & 7;
  char* xw = smem + win * 32768;

  {
    const size_t xoff = (size_t)b * C_ * HW_ + (size_t)(wh * 8 + row) * W_ + wq * 32 + px4;
    float s[4] = {0.f, 0.f, 0.f, 0.f}, q[4] = {0.f, 0.f, 0.f, 0.f};
#pragma unroll
    for (int cc = 0; cc < 32; ++cc) {
      const int ch = cc * 8 + chg;
      f32x4 v = *(const f32x4*)(x + xoff + (size_t)ch * HW_);
#pragma unroll
      for (int i = 0; i < 4; ++i) {
        *xn_at(xw, row * 8 + pc + i, ch) = (_Float16)v[i];
        s[i] += v[i]; q[i] += v[i] * v[i];
      }
    }
    const int tq = win * 64 + row * 8 + pc;
#pragma unroll
    for (int i = 0; i < 4; ++i) {
      red[(tq + i) * 8 + chg] = s[i];
      red[2048 + (tq + i) * 8 + chg] = q[i];
    }
  }
  __syncthreads();
  if (tid < 256) {
    float ss = 0.f, s2 = 0.f;
#pragma unroll
    for (int g = 0; g < 8; ++g) { ss += red[tid * 8 + g]; s2 += red[2048 + tid * 8 + g]; }
    float mu  = ss * (1.f / 256.f);
    float var = s2 * (1.f / 256.f) - mu * mu;
    mrs[tid]       = mu;
    mrs[256 + tid] = rsqrtf(var + 1e-5f);
  }
  __syncthreads();
  {
    char* dst = (char*)xn_ws + (size_t)((b * NWH + wh) * NWW + wq * 4) * 32768;
#pragma unroll
    for (int it = 0; it < 16; ++it) {
      const int a   = (it * 512 + tid) * 16;
      const int w2  = a >> 15;
      const int ab  = a & 32767;
      const int tok = ab >> 9;
      const int chb = ((ab & 511) ^ ((tok & 7) << 4)) >> 1;
      f16x8 hv = *(const f16x8*)(smem + a);
      const float mu = mrs[w2 * 64 + tok], rs = mrs[256 + w2 * 64 + tok];
      f32x4 g0 = *(const f32x4*)(gamma + chb), g1 = *(const f32x4*)(gamma + chb + 4);
      f32x4 b0 = *(const f32x4*)(beta + chb),  b1 = *(const f32x4*)(beta + chb + 4);
#pragma unroll
      for (int j = 0; j < 4; ++j) {
        hv[j]     = (_Float16)(((float)hv[j] - mu) * rs * g0[j] + b0[j]);
        hv[j + 4] = (_Float16)(((float)hv[j + 4] - mu) * rs * g1[j] + b1[j]);
      }
      *(f16x8*)(dst + a) = hv;
    }
  }
}

// ============================ kernel B: attention (v2, low-pressure) =========
// block = 1 window, 256 thr = 4 waves, LDS 81920 -> 2 blocks/CU.
// QKV in 2 groups of 3 tiles (g=0:{q0,q1,v0}, g=1:{k0,k1,v1}) -> acc 48 regs.
// Softmax per-mi (sc live = 16 regs), qa/kb prefetched before p overlays q/k.
__global__ __launch_bounds__(256, 2) void attn_kernel(
    const float* __restrict__ bqkv, const _Float16* __restrict__ w16,
    const _Float16* __restrict__ xn_ws, _Float16* __restrict__ o_ws) {
  extern __shared__ char smem[];
  const int n = blockIdx.x;
  const int tid = threadIdx.x;
  const int w = tid >> 6, lane = tid & 63, lr = lane & 15, lg = lane >> 4;

  {
    const char* src = (const char*)xn_ws + (size_t)n * 32768;
#pragma unroll
    for (int it = 0; it < 8; ++it) {
      const int off = (it * 256 + tid) * 16;
      *(f32x4*)(smem + off) = *(const f32x4*)(src + off);
    }
  }
  __syncthreads();

  char* scr   = smem + 32768 + w * 12288;
  char* kbase = scr + 4096;
  char* vbase = scr + 8192;
  const float sc_q = 0.17677669529663687f;  // 1/sqrt(32)

  f32x4 oacc[2][4][2];
  float oinv[2][4][4];

#pragma unroll
  for (int hl = 0; hl < 2; ++hl) {
    const int hcol  = (2 * w + hl) * 32;
    const int tbase = w * 4 + hl * 2;

    // ---- QKV: two groups of 3 tiles ----
#pragma unroll 1
    for (int g = 0; g < 2; ++g) {
      f32x4 acc[3][4];
#pragma unroll
      for (int tt = 0; tt < 3; ++tt)
#pragma unroll
        for (int mi = 0; mi < 4; ++mi) acc[tt][mi] = (f32x4){0.f, 0.f, 0.f, 0.f};
      const int gt0 = g * 16 + tbase;   // q (g=0) or k (g=1) tiles gt0, gt0+1
      const int gtv = 32 + tbase + g;   // v tile t2=g
#pragma unroll
      for (int kk = 0; kk < 8; ++kk) {
        f16x8 af[4];
#pragma unroll
        for (int mi = 0; mi < 4; ++mi)
          af[mi] = *(const f16x8*)xn_at(smem, mi * 16 + lr, kk * 32 + lg * 8);
        f16x8 b0 = frag16(w16, gt0, kk, lane);
        f16x8 b1 = frag16(w16, gt0 + 1, kk, lane);
        f16x8 b2 = frag16(w16, gtv, kk, lane);
#pragma unroll
        for (int mi = 0; mi < 4; ++mi) {
          acc[0][mi] = __builtin_amdgcn_mfma_f32_16x16x32_f16(af[mi], b0, acc[0][mi], 0, 0, 0);
          acc[1][mi] = __builtin_amdgcn_mfma_f32_16x16x32_f16(af[mi], b1, acc[1][mi], 0, 0, 0);
          acc[2][mi] = __builtin_amdgcn_mfma_f32_16x16x32_f16(af[mi], b2, acc[2][mi], 0, 0, 0);
        }
      }
      if (g == 0) {
#pragma unroll
        for (int tt = 0; tt < 2; ++tt) {
          const float bq = bqkv[hcol + tt * 16 + lr];
#pragma unroll
          for (int mi = 0; mi < 4; ++mi)
#pragma unroll
            for (int i = 0; i < 4; ++i)
              *qk_at(scr, mi * 16 + lg * 4 + i, tt * 16 + lr) =
                  (_Float16)((acc[tt][mi][i] + bq) * sc_q);
        }
      } else {
#pragma unroll
        for (int tt = 0; tt < 2; ++tt) {
          const float bk = bqkv[256 + hcol + tt * 16 + lr];
#pragma unroll
          for (int mi = 0; mi < 4; ++mi)
#pragma unroll
            for (int i = 0; i < 4; ++i)
              *qk_at(kbase, mi * 16 + lg * 4 + i, tt * 16 + lr) =
                  (_Float16)(acc[tt][mi][i] + bk);
        }
      }
      {
        const float bv = bqkv[512 + hcol + g * 16 + lr];
#pragma unroll
        for (int mi = 0; mi < 4; ++mi)
#pragma unroll
          for (int i = 0; i < 4; ++i)
            *vt_at(vbase, g * 16 + lr, mi * 16 + lg * 4 + i) =
                (_Float16)(acc[2][mi][i] + bv);
      }
    }

    // ---- scores + softmax, per-mi fused (qa/kb prefetched; p overlays q/k) --
    f16x8 qa[4], kb[4];
#pragma unroll
    for (int mi = 0; mi < 4; ++mi)
      qa[mi] = *(const f16x8*)qk_at(scr, mi * 16 + lr, lg * 8);
#pragma unroll
    for (int ni = 0; ni < 4; ++ni)
      kb[ni] = *(const f16x8*)qk_at(kbase, ni * 16 + lr, lg * 8);
#pragma unroll
    for (int mi = 0; mi < 4; ++mi) {
      f32x4 s4[4];
#pragma unroll
      for (int ni = 0; ni < 4; ++ni) {
        f32x4 z = {0.f, 0.f, 0.f, 0.f};
        s4[ni] = __builtin_amdgcn_mfma_f32_16x16x32_f16(qa[mi], kb[ni], z, 0, 0, 0);
      }
#pragma unroll
      for (int i = 0; i < 4; ++i) {
        float m = fmaxf(fmaxf(s4[0][i], s4[1][i]), fmaxf(s4[2][i], s4[3][i]));
        m = fmaxf(m, __shfl_xor(m, 1));
        m = fmaxf(m, __shfl_xor(m, 2));
        m = fmaxf(m, __shfl_xor(m, 4));
        m = fmaxf(m, __shfl_xor(m, 8));
        float s = 0.f;
#pragma unroll
        for (int ni = 0; ni < 4; ++ni) {
          float e = __expf(s4[ni][i] - m);
          s4[ni][i] = e;
          s += e;
        }
        s += __shfl_xor(s, 1);
        s += __shfl_xor(s, 2);
        s += __shfl_xor(s, 4);
        s += __shfl_xor(s, 8);
        oinv[hl][mi][i] = 1.f / s;
      }
#pragma unroll
      for (int ni = 0; ni < 4; ++ni)
#pragma unroll
        for (int i = 0; i < 4; ++i)
          *p_at(scr, mi * 16 + lg * 4 + i, ni * 16 + lr) = (_Float16)s4[ni][i];
    }

    // ---- PV ----
#pragma unroll
    for (int mi = 0; mi < 4; ++mi)
#pragma unroll
      for (int nt2 = 0; nt2 < 2; ++nt2)
        oacc[hl][mi][nt2] = (f32x4){0.f, 0.f, 0.f, 0.f};
#pragma unroll
    for (int ks2 = 0; ks2 < 2; ++ks2) {
      f16x8 pa[4];
#pragma unroll
      for (int mi = 0; mi < 4; ++mi)
        pa[mi] = *(const f16x8*)p_at(scr, mi * 16 + lr, ks2 * 32 + lg * 8);
#pragma unroll
      for (int nt2 = 0; nt2 < 2; ++nt2) {
        f16x8 vb = *(const f16x8*)vt_at(vbase, nt2 * 16 + lr, ks2 * 32 + lg * 8);
#pragma unroll
        for (int mi = 0; mi < 4; ++mi)
          oacc[hl][mi][nt2] = __builtin_amdgcn_mfma_f32_16x16x32_f16(
              pa[mi], vb, oacc[hl][mi][nt2], 0, 0, 0);
      }
    }
#pragma unroll
    for (int mi = 0; mi < 4; ++mi)
#pragma unroll
      for (int nt2 = 0; nt2 < 2; ++nt2)
#pragma unroll
        for (int i = 0; i < 4; ++i)
          oacc[hl][mi][nt2][i] *= oinv[hl][mi][i];
  }
  __syncthreads();  // all waves done reading xn

  // merged-head o -> xn region (swizzled)
#pragma unroll
  for (int hl = 0; hl < 2; ++hl) {
    const int hcol = (2 * w + hl) * 32;
#pragma unroll
    for (int mi = 0; mi < 4; ++mi)
#pragma unroll
      for (int nt2 = 0; nt2 < 2; ++nt2)
#pragma unroll
        for (int i = 0; i < 4; ++i)
          *xn_at(smem, mi * 16 + lg * 4 + i, hcol + nt2 * 16 + lr) =
              (_Float16)oacc[hl][mi][nt2][i];
  }
  __syncthreads();

  {
    char* dst = (char*)o_ws + (size_t)n * 32768;
#pragma unroll
    for (int it = 0; it < 8; ++it) {
      const int off = (it * 256 + tid) * 16;
      *(f32x4*)(dst + off) = *(const f32x4*)(smem + off);
    }
  }
}

// ============================ kernel C: out-proj =============================
__global__ __launch_bounds__(512, 1) void outproj_kernel(
    const _Float16* __restrict__ o_ws, const _Float16* __restrict__ w16,
    const float* __restrict__ bout, float* __restrict__ out) {
  extern __shared__ char smem[];
  const int n0 = blockIdx.x;
  const int b  = n0 / 196;
  const int rem = n0 % 196;
  const int wh = rem / 7;
  const int wq = rem % 7;
  const int tid = threadIdx.x;
  const int w = tid >> 6, lane = tid & 63, lr = lane & 15, lg = lane >> 4;

  {
    const char* src = (const char*)o_ws + (size_t)((b * NWH + wh) * NWW + wq * 4) * 32768;
#pragma unroll
    for (int it = 0; it < 16; ++it) {
      const int off = (it * 512 + tid) * 16;
      *(f32x4*)(smem + off) = *(const f32x4*)(src + off);
    }
  }
  __syncthreads();

  f32x4 acc[4][2][4];  // [win][ntl][mi]
#pragma unroll
  for (int wi = 0; wi < 4; ++wi)
#pragma unroll
    for (int t = 0; t < 2; ++t)
#pragma unroll
      for (int mi = 0; mi < 4; ++mi) acc[wi][t][mi] = (f32x4){0.f, 0.f, 0.f, 0.f};

#pragma unroll
  for (int kk = 0; kk < 8; ++kk) {
    f16x8 bf0 = frag16(w16, 48 + w * 2 + 0, kk, lane);
    f16x8 bf1 = frag16(w16, 48 + w * 2 + 1, kk, lane);
#pragma unroll
    for (int wi = 0; wi < 4; ++wi) {
      f16x8 af[4];
#pragma unroll
      for (int mi = 0; mi < 4; ++mi)
        af[mi] = *(const f16x8*)xn_at(smem + wi * 32768, mi * 16 + lr, kk * 32 + lg * 8);
#pragma unroll
      for (int mi = 0; mi < 4; ++mi) {
        acc[wi][0][mi] = __builtin_amdgcn_mfma_f32_16x16x32_f16(af[mi], bf0, acc[wi][0][mi], 0, 0, 0);
        acc[wi][1][mi] = __builtin_amdgcn_mfma_f32_16x16x32_f16(af[mi], bf1, acc[wi][1][mi], 0, 0, 0);
      }
    }
  }

#pragma unroll
  for (int ntl = 0; ntl < 2; ++ntl) {
    const int och = w * 32 + ntl * 16 + lr;
    const float bias = bout[och];
    float* ob = out + ((size_t)(b * C_ + och) * H_ + wh * 8) * W_ + wq * 32;
#pragma unroll
    for (int mi = 0; mi < 4; ++mi) {
      const int tb = mi * 16 + lg * 4;
      const int ro = (tb >> 3) * W_ + (tb & 7);
#pragma unroll
      for (int wi = 0; wi < 4; ++wi) {
        f32x4 ov;
#pragma unroll
        for (int i = 0; i < 4; ++i) ov[i] = acc[wi][ntl][mi][i] + bias;
        *(f32x4*)&ob[ro + wi * 8] = ov;
      }
    }
  }
}

extern "C" void kernel_launch(void* const* d_in, const int* in_sizes, int n_in,
                              void* d_out, int out_size, void* d_ws, size_t ws_size,
                              hipStream_t stream) {
  (void)in_sizes; (void)n_in; (void)out_size; (void)ws_size;
  const float* x     = (const float*)d_in[0];
  const float* gamma = (const float*)d_in[1];
  const float* beta  = (const float*)d_in[2];
  const float* wqkv  = (const float*)d_in[3];
  const float* bqkv  = (const float*)d_in[4];
  const float* wout  = (const float*)d_in[5];
  const float* bout  = (const float*)d_in[6];
  float* out = (float*)d_out;

  _Float16* w16   = (_Float16*)d_ws;
  _Float16* xn_ws = (_Float16*)((char*)d_ws + XN_OFF);
  _Float16* o_ws  = (_Float16*)((char*)d_ws + O_OFF);
  static int attr_set = 0;
  if (!attr_set) {
    (void)hipFuncSetAttribute((const void*)prep_kernel,
                              hipFuncAttributeMaxDynamicSharedMemorySize, 149504);
    (void)hipFuncSetAttribute((const void*)attn_kernel,
                              hipFuncAttributeMaxDynamicSharedMemorySize, 81920);
    (void)hipFuncSetAttribute((const void*)outproj_kernel,
                              hipFuncAttributeMaxDynamicSharedMemorySize, 131072);
    attr_set = 1;
  }
  wcvt_kernel<<<NFRAG / 256, 256, 0, stream>>>(wqkv, wout, w16);
  prep_kernel<<<NQUAD, 512, 149504, stream>>>(x, gamma, beta, xn_ws);
  attn_kernel<<<NWIN, 256, 81920, stream>>>(bqkv, w16, xn_ws, o_ws);
  outproj_kernel<<<NQUAD, 512, 131072, stream>>>(o_ws, w16, bout, out);
}

// Round 7
// 531.571 us; speedup vs baseline: 1.4350x; 1.4350x over previous
//
#include <hip/hip_runtime.h>
#include <hip/hip_fp16.h>

#define C_   256
#define H_   224
#define W_   224
#define HW_  (224 * 224)
#define NWH  28
#define NWW  28
#define NWIN 3136
#define NQUAD 784
#define NTILE 64
#define NFRAG (NTILE * 8 * 64)
#define WPC   784              // windows per chunk (4 chunks)

#define XN_OFF  (1ULL << 20)
#define QKV_OFF (XN_OFF + (unsigned long long)NWIN * 32768ULL)   // 103809024
#define WS_NEED (QKV_OFF + (unsigned long long)WPC * 98304ULL)   // 180879360 (< R5-proven 207MB)

typedef _Float16 f16x8 __attribute__((ext_vector_type(8)));
typedef float    f32x4 __attribute__((ext_vector_type(4)));

// ---- byte-offset swizzles (bijective XOR; 16B-aligned) ----------------------
__device__ __forceinline__ int xn_off(int row, int col) {
  return (row * 512 + col * 2) ^ ((row & 7) << 4);
}
__device__ __forceinline__ int qk_off(int row, int col) {
  return (row * 64 + col * 2) ^ (((row >> 1) & 3) << 4);
}
__device__ __forceinline__ int vt_off(int d, int k) {
  return (d * 128 + k * 2) ^ ((d & 7) << 4);
}
__device__ __forceinline__ int p_off(int row, int col) {
  return (row * 128 + col * 2) ^ ((row & 7) << 4);
}
__device__ __forceinline__ _Float16* xn_at(char* s, int r, int c) { return (_Float16*)(s + xn_off(r, c)); }

// ---- weight fp32 -> fragment-major fp16 ------------------------------------
__global__ void wcvt_kernel(const float* __restrict__ wqkv,
                            const float* __restrict__ wout,
                            _Float16* __restrict__ dst) {
  int f = blockIdx.x * blockDim.x + threadIdx.x;
  if (f >= NFRAG) return;
  int lane = f & 63, kk = (f >> 6) & 7, tile = f >> 9;
  int row = tile * 16 + (lane & 15);
  int col = kk * 32 + (lane >> 4) * 8;
  const float* src = (tile < 48) ? (wqkv + row * 256 + col)
                                 : (wout + (row - 768) * 256 + col);
  f32x4 a = *(const f32x4*)src;
  f32x4 b2 = *(const f32x4*)(src + 4);
  f16x8 r;
#pragma unroll
  for (int q = 0; q < 4; ++q) { r[q] = (_Float16)a[q]; r[q + 4] = (_Float16)b2[q]; }
  *(f16x8*)(dst + (size_t)f * 8) = r;
}

// ============================ kernel A: prep (unchanged, proven) =============
__global__ __launch_bounds__(512, 1) void prep_kernel(
    const float* __restrict__ x, const float* __restrict__ gamma,
    const float* __restrict__ beta, _Float16* __restrict__ xn_ws) {
  extern __shared__ char smem[];
  float* red = (float*)(smem + 131072);
  float* mrs = (float*)(smem + 147456);
  const int n0 = blockIdx.x;
  const int b  = n0 / 196;
  const int rem = n0 % 196;
  const int wh = rem / 7;
  const int wq = rem % 7;
  const int tid = threadIdx.x;
  const int px4 = (tid & 7) * 4;
  const int row = (tid >> 3) & 7;
  const int chg = tid >> 6;
  const int win = px4 >> 3;
  const int pc  = px4 & 7;
  char* xw = smem + win * 32768;

  {
    const size_t xoff = (size_t)b * C_ * HW_ + (size_t)(wh * 8 + row) * W_ + wq * 32 + px4;
    float s[4] = {0.f, 0.f, 0.f, 0.f}, q[4] = {0.f, 0.f, 0.f, 0.f};
#pragma unroll
    for (int cc = 0; cc < 32; ++cc) {
      const int ch = cc * 8 + chg;
      f32x4 v = *(const f32x4*)(x + xoff + (size_t)ch * HW_);
#pragma unroll
      for (int i = 0; i < 4; ++i) {
        *xn_at(xw, row * 8 + pc + i, ch) = (_Float16)v[i];
        s[i] += v[i]; q[i] += v[i] * v[i];
      }
    }
    const int tq = win * 64 + row * 8 + pc;
#pragma unroll
    for (int i = 0; i < 4; ++i) {
      red[(tq + i) * 8 + chg] = s[i];
      red[2048 + (tq + i) * 8 + chg] = q[i];
    }
  }
  __syncthreads();
  if (tid < 256) {
    float ss = 0.f, s2 = 0.f;
#pragma unroll
    for (int g = 0; g < 8; ++g) { ss += red[tid * 8 + g]; s2 += red[2048 + tid * 8 + g]; }
    float mu  = ss * (1.f / 256.f);
    float var = s2 * (1.f / 256.f) - mu * mu;
    mrs[tid]       = mu;
    mrs[256 + tid] = rsqrtf(var + 1e-5f);
  }
  __syncthreads();
  {
    char* dst = (char*)xn_ws + (size_t)((b * NWH + wh) * NWW + wq * 4) * 32768;
#pragma unroll
    for (int it = 0; it < 16; ++it) {
      const int a   = (it * 512 + tid) * 16;
      const int w2  = a >> 15;
      const int ab  = a & 32767;
      const int tok = ab >> 9;
      const int chb = ((ab & 511) ^ ((tok & 7) << 4)) >> 1;
      f16x8 hv = *(const f16x8*)(smem + a);
      const float mu = mrs[w2 * 64 + tok], rs = mrs[256 + w2 * 64 + tok];
      f32x4 g0 = *(const f32x4*)(gamma + chb), g1 = *(const f32x4*)(gamma + chb + 4);
      f32x4 b0 = *(const f32x4*)(beta + chb),  b1 = *(const f32x4*)(beta + chb + 4);
#pragma unroll
      for (int j = 0; j < 4; ++j) {
        hv[j]     = (_Float16)(((float)hv[j] - mu) * rs * g0[j] + b0[j]);
        hv[j + 4] = (_Float16)(((float)hv[j + 4] - mu) * rs * g1[j] + b1[j]);
      }
      *(f16x8*)(dst + a) = hv;
    }
  }
}

// ============================ kernel B: QKV GEMM (weight-stationary) =========
// grid = 3 sections x 98 groups; block = 512 thr = 8 waves; 1 wave = 1 window.
// LDS: [0,131072) section weights (frag-major); [131072,163840) 8 x 4KB stage.
// Each wave: A-frags (32 f16x8 regs), nt-loop over 8 head-tiles, acc 32 regs.
__global__ __launch_bounds__(512, 2) void qkvgemm_kernel(
    const float* __restrict__ bqkv, const _Float16* __restrict__ w16,
    const _Float16* __restrict__ xn_ws, _Float16* __restrict__ qkv_ws,
    int winBase) {
  extern __shared__ char smem[];
  const int tid = threadIdx.x;
  const int sec = blockIdx.x / 98;   // 0=q 1=k 2=v
  const int wg  = blockIdx.x % 98;
  const int w = tid >> 6, lane = tid & 63, lr = lane & 15, lg = lane >> 4;

  // stage section weights: 131072B contiguous from w16 + sec*131072
  {
    const f32x4* src = (const f32x4*)((const char*)w16 + (size_t)sec * 131072);
    f32x4* dst = (f32x4*)smem;
#pragma unroll
    for (int it = 0; it < 16; ++it)
      dst[it * 512 + tid] = src[it * 512 + tid];
  }
  __syncthreads();

  const int win = winBase + wg * 8 + w;
  // A-fragments for this wave's window, held in registers
  f16x8 af[4][8];
  {
    const char* xb = (const char*)xn_ws + (size_t)win * 32768;
#pragma unroll
    for (int mi = 0; mi < 4; ++mi)
#pragma unroll
      for (int kk = 0; kk < 8; ++kk)
        af[mi][kk] = *(const f16x8*)(xb + xn_off(mi * 16 + lr, kk * 32 + lg * 8));
  }

  char* stage = smem + 131072 + w * 4096;
  char* blob  = (char*)qkv_ws + (size_t)(win - winBase) * 98304 + (size_t)sec * 32768;
  const float sc = (sec == 0) ? 0.17677669529663687f : 1.0f;

#pragma unroll 1
  for (int nt = 0; nt < 8; ++nt) {           // nt == head
    f32x4 acc[2][4];
#pragma unroll
    for (int t = 0; t < 2; ++t)
#pragma unroll
      for (int mi = 0; mi < 4; ++mi) acc[t][mi] = (f32x4){0.f, 0.f, 0.f, 0.f};
#pragma unroll
    for (int kk = 0; kk < 8; ++kk) {
      f16x8 b0 = *(const f16x8*)(smem + (size_t)(((nt * 2 + 0) * 8 + kk) * 64 + lane) * 16);
      f16x8 b1 = *(const f16x8*)(smem + (size_t)(((nt * 2 + 1) * 8 + kk) * 64 + lane) * 16);
#pragma unroll
      for (int mi = 0; mi < 4; ++mi) {
        acc[0][mi] = __builtin_amdgcn_mfma_f32_16x16x32_f16(af[mi][kk], b0, acc[0][mi], 0, 0, 0);
        acc[1][mi] = __builtin_amdgcn_mfma_f32_16x16x32_f16(af[mi][kk], b1, acc[1][mi], 0, 0, 0);
      }
    }
    // epilogue -> wave-private LDS stage (attn-native swizzle)
#pragma unroll
    for (int t = 0; t < 2; ++t) {
      const float bias = bqkv[sec * 256 + nt * 32 + t * 16 + lr];
#pragma unroll
      for (int mi = 0; mi < 4; ++mi)
#pragma unroll
        for (int i = 0; i < 4; ++i) {
          const int row = mi * 16 + lg * 4 + i;   // token
          const float v = (acc[t][mi][i] + bias) * sc;
          if (sec < 2)
            *(_Float16*)(stage + qk_off(row, t * 16 + lr)) = (_Float16)v;
          else
            *(_Float16*)(stage + vt_off(t * 16 + lr, row)) = (_Float16)v;
        }
    }
    // dense 4KB dump (wave-private, no barrier needed)
    char* bd = blob + nt * 4096;
#pragma unroll
    for (int j = 0; j < 4; ++j)
      *(f32x4*)(bd + lane * 64 + j * 16) = *(const f32x4*)(stage + lane * 64 + j * 16);
  }
}

// ============================ kernel C: attention core (no weights) ==========
// block = 1 window, 256 thr = 4 waves (wave w: heads 2w,2w+1).
// LDS: [0,32768) p per-wave 8KB ; [32768,65536) merged-o [64][256] swizzled.
__global__ __launch_bounds__(256, 2) void attncore_kernel(
    const _Float16* __restrict__ qkv_ws, _Float16* __restrict__ o_ws,
    int winBase) {
  extern __shared__ char smem[];
  const int nl = blockIdx.x;              // chunk-local window
  const int n  = winBase + nl;            // global window
  const int tid = threadIdx.x;
  const int w = tid >> 6, lane = tid & 63, lr = lane & 15, lg = lane >> 4;
  const char* base = (const char*)qkv_ws + (size_t)nl * 98304;
  char* pbuf = smem + w * 8192;
  char* obuf = smem + 32768;

  f32x4 oacc[2][4][2];
  float oinv[2][4][4];

#pragma unroll
  for (int hl = 0; hl < 2; ++hl) {
    const int head = 2 * w + hl;
    const char* qb = base + (size_t)head * 4096;
    const char* kbp = base + 32768 + (size_t)head * 4096;
    const char* vbp = base + 65536 + (size_t)head * 4096;

    f16x8 qa[4], kb[4];
#pragma unroll
    for (int mi = 0; mi < 4; ++mi)
      qa[mi] = *(const f16x8*)(qb + qk_off(mi * 16 + lr, lg * 8));
#pragma unroll
    for (int ni = 0; ni < 4; ++ni)
      kb[ni] = *(const f16x8*)(kbp + qk_off(ni * 16 + lr, lg * 8));
    f32x4 sc[4][4];
#pragma unroll
    for (int mi = 0; mi < 4; ++mi)
#pragma unroll
      for (int ni = 0; ni < 4; ++ni) {
        f32x4 z = {0.f, 0.f, 0.f, 0.f};
        sc[mi][ni] = __builtin_amdgcn_mfma_f32_16x16x32_f16(qa[mi], kb[ni], z, 0, 0, 0);
      }
    // softmax (row r = mi*16+lg*4+i lives in 16 lanes of group lg)
#pragma unroll
    for (int mi = 0; mi < 4; ++mi)
#pragma unroll
      for (int i = 0; i < 4; ++i) {
        float m = fmaxf(fmaxf(sc[mi][0][i], sc[mi][1][i]),
                        fmaxf(sc[mi][2][i], sc[mi][3][i]));
        m = fmaxf(m, __shfl_xor(m, 1));
        m = fmaxf(m, __shfl_xor(m, 2));
        m = fmaxf(m, __shfl_xor(m, 4));
        m = fmaxf(m, __shfl_xor(m, 8));
        float s = 0.f;
#pragma unroll
        for (int ni = 0; ni < 4; ++ni) {
          float e = __expf(sc[mi][ni][i] - m);
          sc[mi][ni][i] = e;
          s += e;
        }
        s += __shfl_xor(s, 1);
        s += __shfl_xor(s, 2);
        s += __shfl_xor(s, 4);
        s += __shfl_xor(s, 8);
        oinv[hl][mi][i] = 1.f / s;
      }
#pragma unroll
    for (int mi = 0; mi < 4; ++mi)
#pragma unroll
      for (int ni = 0; ni < 4; ++ni)
#pragma unroll
        for (int i = 0; i < 4; ++i)
          *(_Float16*)(pbuf + p_off(mi * 16 + lg * 4 + i, ni * 16 + lr)) =
              (_Float16)sc[mi][ni][i];
    // PV
#pragma unroll
    for (int mi = 0; mi < 4; ++mi)
#pragma unroll
      for (int nt2 = 0; nt2 < 2; ++nt2)
        oacc[hl][mi][nt2] = (f32x4){0.f, 0.f, 0.f, 0.f};
#pragma unroll
    for (int ks2 = 0; ks2 < 2; ++ks2) {
      f16x8 pa[4];
#pragma unroll
      for (int mi = 0; mi < 4; ++mi)
        pa[mi] = *(const f16x8*)(pbuf + p_off(mi * 16 + lr, ks2 * 32 + lg * 8));
#pragma unroll
      for (int nt2 = 0; nt2 < 2; ++nt2) {
        f16x8 vb = *(const f16x8*)(vbp + vt_off(nt2 * 16 + lr, ks2 * 32 + lg * 8));
#pragma unroll
        for (int mi = 0; mi < 4; ++mi)
          oacc[hl][mi][nt2] = __builtin_amdgcn_mfma_f32_16x16x32_f16(
              pa[mi], vb, oacc[hl][mi][nt2], 0, 0, 0);
      }
    }
#pragma unroll
    for (int mi = 0; mi < 4; ++mi)
#pragma unroll
      for (int nt2 = 0; nt2 < 2; ++nt2)
#pragma unroll
        for (int i = 0; i < 4; ++i)
          oacc[hl][mi][nt2][i] *= oinv[hl][mi][i];
  }

  // merged-head o -> LDS (swizzled [64][256])
#pragma unroll
  for (int hl = 0; hl < 2; ++hl) {
    const int hcol = (2 * w + hl) * 32;
#pragma unroll
    for (int mi = 0; mi < 4; ++mi)
#pragma unroll
      for (int nt2 = 0; nt2 < 2; ++nt2)
#pragma unroll
        for (int i = 0; i < 4; ++i)
          *xn_at(obuf, mi * 16 + lg * 4 + i, hcol + nt2 * 16 + lr) =
              (_Float16)oacc[hl][mi][nt2][i];
  }
  __syncthreads();
  {
    char* dst = (char*)o_ws + (size_t)n * 32768;
#pragma unroll
    for (int it = 0; it < 8; ++it) {
      const int off = (it * 256 + tid) * 16;
      *(f32x4*)(dst + off) = *(const f32x4*)(obuf + off);
    }
  }
}

// ============================ kernel D: out-proj (unchanged, proven) =========
__device__ __forceinline__ f16x8 frag16(const _Float16* __restrict__ w16,
                                        int gt, int kk, int lane) {
  return *(const f16x8*)(w16 + ((size_t)((gt * 8 + kk) * 64 + lane)) * 8);
}
__global__ __launch_bounds__(512, 1) void outproj_kernel(
    const _Float16* __restrict__ o_ws, const _Float16* __restrict__ w16,
    const float* __restrict__ bout, float* __restrict__ out) {
  extern __shared__ char smem[];
  const int n0 = blockIdx.x;
  const int b  = n0 / 196;
  const int rem = n0 % 196;
  const int wh = rem / 7;
  const int wq = rem % 7;
  const int tid = threadIdx.x;
  const int w = tid >> 6, lane = tid & 63, lr = lane & 15, lg = lane >> 4;

  {
    const char* src = (const char*)o_ws + (size_t)((b * NWH + wh) * NWW + wq * 4) * 32768;
#pragma unroll
    for (int it = 0; it < 16; ++it) {
      const int off = (it * 512 + tid) * 16;
      *(f32x4*)(smem + off) = *(const f32x4*)(src + off);
    }
  }
  __syncthreads();

  f32x4 acc[4][2][4];
#pragma unroll
  for (int wi = 0; wi < 4; ++wi)
#pragma unroll
    for (int t = 0; t < 2; ++t)
#pragma unroll
      for (int mi = 0; mi < 4; ++mi) acc[wi][t][mi] = (f32x4){0.f, 0.f, 0.f, 0.f};

#pragma unroll
  for (int kk = 0; kk < 8; ++kk) {
    f16x8 bf0 = frag16(w16, 48 + w * 2 + 0, kk, lane);
    f16x8 bf1 = frag16(w16, 48 + w * 2 + 1, kk, lane);
#pragma unroll
    for (int wi = 0; wi < 4; ++wi) {
      f16x8 af[4];
#pragma unroll
      for (int mi = 0; mi < 4; ++mi)
        af[mi] = *(const f16x8*)xn_at(smem + wi * 32768, mi * 16 + lr, kk * 32 + lg * 8);
#pragma unroll
      for (int mi = 0; mi < 4; ++mi) {
        acc[wi][0][mi] = __builtin_amdgcn_mfma_f32_16x16x32_f16(af[mi], bf0, acc[wi][0][mi], 0, 0, 0);
        acc[wi][1][mi] = __builtin_amdgcn_mfma_f32_16x16x32_f16(af[mi], bf1, acc[wi][1][mi], 0, 0, 0);
      }
    }
  }

#pragma unroll
  for (int ntl = 0; ntl < 2; ++ntl) {
    const int och = w * 32 + ntl * 16 + lr;
    const float bias = bout[och];
    float* ob = out + ((size_t)(b * C_ + och) * H_ + wh * 8) * W_ + wq * 32;
#pragma unroll
    for (int mi = 0; mi < 4; ++mi) {
      const int tb = mi * 16 + lg * 4;
      const int ro = (tb >> 3) * W_ + (tb & 7);
#pragma unroll
      for (int wi = 0; wi < 4; ++wi) {
        f32x4 ov;
#pragma unroll
        for (int i = 0; i < 4; ++i) ov[i] = acc[wi][ntl][mi][i] + bias;
        *(f32x4*)&ob[ro + wi * 8] = ov;
      }
    }
  }
}

extern "C" void kernel_launch(void* const* d_in, const int* in_sizes, int n_in,
                              void* d_out, int out_size, void* d_ws, size_t ws_size,
                              hipStream_t stream) {
  (void)in_sizes; (void)n_in; (void)out_size;
  const float* x     = (const float*)d_in[0];
  const float* gamma = (const float*)d_in[1];
  const float* beta  = (const float*)d_in[2];
  const float* wqkv  = (const float*)d_in[3];
  const float* bqkv  = (const float*)d_in[4];
  const float* wout  = (const float*)d_in[5];
  const float* bout  = (const float*)d_in[6];
  float* out = (float*)d_out;

  // ws_size >= 207MB was proven in R5; WS_NEED here is 172.5MB.
  _Float16* w16    = (_Float16*)d_ws;
  _Float16* xn_ws  = (_Float16*)((char*)d_ws + XN_OFF);   // overlaid by o blobs
  _Float16* qkv_ws = (_Float16*)((char*)d_ws + QKV_OFF);

  static int attr_set = 0;
  if (!attr_set) {
    (void)hipFuncSetAttribute((const void*)prep_kernel,
                              hipFuncAttributeMaxDynamicSharedMemorySize, 149504);
    (void)hipFuncSetAttribute((const void*)qkvgemm_kernel,
                              hipFuncAttributeMaxDynamicSharedMemorySize, 163840);
    (void)hipFuncSetAttribute((const void*)attncore_kernel,
                              hipFuncAttributeMaxDynamicSharedMemorySize, 65536);
    (void)hipFuncSetAttribute((const void*)outproj_kernel,
                              hipFuncAttributeMaxDynamicSharedMemorySize, 131072);
    attr_set = 1;
  }

  wcvt_kernel<<<NFRAG / 256, 256, 0, stream>>>(wqkv, wout, w16);
  prep_kernel<<<NQUAD, 512, 149504, stream>>>(x, gamma, beta, xn_ws);
  for (int c = 0; c < 4; ++c) {
    qkvgemm_kernel<<<294, 512, 163840, stream>>>(bqkv, w16, xn_ws, qkv_ws, c * WPC);
    attncore_kernel<<<WPC, 256, 65536, stream>>>(qkv_ws, xn_ws /*o overlay*/, c * WPC);
  }
  outproj_kernel<<<NQUAD, 512, 131072, stream>>>(xn_ws /*o blobs*/, w16, bout, out);
}